// Round 9
// baseline (337.785 us; speedup 1.0000x reference)
//
#include <hip/hip_runtime.h>
#include <math.h>

typedef __attribute__((ext_vector_type(8))) short short8;
typedef __attribute__((ext_vector_type(4))) float floatx4;

__device__ __forceinline__ unsigned short bf16r(float f) {
  union { float f; unsigned int u; } v; v.f = f;
  unsigned int u = v.u;
  return (unsigned short)((u + 0x7fffu + ((u >> 16) & 1u)) >> 16);
}
// round-half-up pack (sampling path)
__device__ __forceinline__ unsigned int bf16h(float f) {
  union { float f; unsigned int u; } v; v.f = f;
  return (v.u + 0x8000u) >> 16;
}
__device__ __forceinline__ float bf2f(unsigned int u) {
  union { unsigned int u; float f; } v; v.u = u << 16; return v.f;
}

// ---------------------------------------------------------------------------
// K0: weight prep (bf16, MFMA-frag layouts) + fused tables
// ---------------------------------------------------------------------------
__global__ __launch_bounds__(256) void k_prep(
    const float* __restrict__ w_dcn, const float* __restrict__ w_off,
    const float* __restrict__ b_dcn,
    const float* __restrict__ bn_g, const float* __restrict__ bn_b,
    const float* __restrict__ bn_m, const float* __restrict__ bn_v,
    const float* __restrict__ w_up, const float* __restrict__ w1x1,
    unsigned short* __restrict__ wt_dcn, unsigned short* __restrict__ wt_off,
    float* __restrict__ vtab, float* __restrict__ bntab) {
  int e = blockIdx.x * 256 + threadIdx.x;
  if (e < 294912) {
    int cc = e & 31, o = (e >> 5) & 127, s = e >> 12;
    int k = s % 9, cg = s / 9, c = cg * 32 + cc;
    wt_dcn[e] = bf16r(w_dcn[(o * 256 + c) * 9 + k]);
  }
  if (e < 73728) {
    int cc = e & 31, oc = (e >> 5) & 31, s = e >> 10;
    int k = s % 9, cg = s / 9, c = cg * 32 + cc;
    wt_off[e] = (oc < 27) ? bf16r(w_off[(oc * 256 + c) * 9 + k]) : (unsigned short)0;
  }
  if (e < 2048) {
    int o = e >> 4;
    vtab[e] = w1x1[o] * w_up[e];
  }
  if (e < 128) {
    float g = bn_g[e] * rsqrtf(bn_v[e] + 1e-5f);
    bntab[e] = g;
    bntab[128 + e] = (b_dcn[e] - bn_m[e]) * g + bn_b[e];
  }
}

// ---------------------------------------------------------------------------
// K0b: x (fp32 NCHW) -> xT (bf16, [b][pixel][c]); float4 loads (4px/thread)
// ---------------------------------------------------------------------------
__global__ __launch_bounds__(256) void k_xt(
    const float* __restrict__ x, unsigned short* __restrict__ xT) {
  __shared__ unsigned short sx[32 * 264];
  int b = blockIdx.x >> 7, px0 = (blockIdx.x & 127) * 32;
  int t = threadIdx.x;
  int pg = (t & 7) * 4, cg = t >> 3;   // 8 px-quads x 32 c-groups of 8
  const float* xsrc = x + (((size_t)(b * 256 + cg * 8)) << 12) + px0 + pg;
#pragma unroll
  for (int cc = 0; cc < 8; ++cc) {
    float4 v = *(const float4*)&xsrc[(size_t)cc << 12];
    int c = cg * 8 + cc;
    sx[(pg + 0) * 264 + c] = bf16r(v.x);
    sx[(pg + 1) * 264 + c] = bf16r(v.y);
    sx[(pg + 2) * 264 + c] = bf16r(v.z);
    sx[(pg + 3) * 264 + c] = bf16r(v.w);
  }
  __syncthreads();
#pragma unroll
  for (int j = 0; j < 4; ++j) {
    int unit = t + j * 256;
    int p = unit >> 5, chunk = unit & 31;
    uint4 v = *(const uint4*)&sx[p * 264 + chunk * 8];
    *(uint4*)&xT[((size_t)((b << 12) + px0 + p)) * 256 + chunk * 8] = v;
  }
}

// ---------------------------------------------------------------------------
// K1: offset conv via MFMA, zero LDS / zero barriers, batched loads (MLP).
// ---------------------------------------------------------------------------
__global__ __launch_bounds__(256, 2) void k_offconv(
    const unsigned short* __restrict__ xT, const unsigned short* __restrict__ wt_off,
    const float* __restrict__ b_off, unsigned short* __restrict__ om) {
  int b = blockIdx.x >> 6, row = blockIdx.x & 63;
  int t = threadIdx.x, lane = t & 63, wvx = t >> 6;
  int l15 = lane & 15, quad = lane >> 4;
  int xcol = wvx * 16 + l15;
  const unsigned short* xb = xT + (((size_t)b) << 12) * 256;
  const short8 zz = {0, 0, 0, 0, 0, 0, 0, 0};

  int pixk[9]; bool vk[9];
#pragma unroll
  for (int k = 0; k < 9; ++k) {
    int yy = row + k / 3 - 1, xx = xcol + k % 3 - 1;
    vk[k] = ((unsigned)yy < 64u) & ((unsigned)xx < 64u);
    pixk[k] = vk[k] ? (yy * 64 + xx) : 0;
  }

  floatx4 acc[2];
  acc[0] = (floatx4){0.f, 0.f, 0.f, 0.f};
  acc[1] = (floatx4){0.f, 0.f, 0.f, 0.f};

  for (int cg = 0; cg < 8; ++cg) {
    int cb = cg * 32 + quad * 8;
    short8 bx[9];
#pragma unroll
    for (int k = 0; k < 9; ++k) {
      short8 v = *(const short8*)&xb[(size_t)pixk[k] * 256 + cb];
      bx[k] = vk[k] ? v : zz;
    }
#pragma unroll
    for (int k = 0; k < 9; ++k) {
      const unsigned short* wp = wt_off + (size_t)(cg * 9 + k) * 1024;
      short8 a0 = *(const short8*)&wp[l15 * 32 + quad * 8];
      short8 a1 = *(const short8*)&wp[(16 + l15) * 32 + quad * 8];
      acc[0] = __builtin_amdgcn_mfma_f32_16x16x32_bf16(a0, bx[k], acc[0], 0, 0, 0);
      acc[1] = __builtin_amdgcn_mfma_f32_16x16x32_bf16(a1, bx[k], acc[1], 0, 0, 0);
    }
  }
#pragma unroll
  for (int ot = 0; ot < 2; ++ot)
#pragma unroll
    for (int r = 0; r < 4; ++r) {
      int o = ot * 16 + quad * 4 + r;
      if (o < 27)
        om[(((size_t)(b * 27 + o)) << 12) + row * 64 + xcol] = bf16r(acc[ot][r] + b_off[o]);
    }
}

// ---------------------------------------------------------------------------
// K2: DCNv2 via MFMA + fused BN/ReLU + fused (upsample x 1x1) -> R.
// NO LDS W staging, NO K-loop barriers: A-frags direct from global (W is
// 576 KB -> L2-resident). grid=1024 (32px/block) -> 4 blocks/CU, 16 waves/CU.
// Wave tile 64o x 16px; o-halves pair-reduce via 2KB LDS in epilogue.
// ---------------------------------------------------------------------------
__global__ __launch_bounds__(256, 4) void k_dcn(
    const unsigned short* __restrict__ xT, const unsigned short* __restrict__ wt,
    const unsigned short* __restrict__ om, const float* __restrict__ vtab,
    const float* __restrict__ bntab, float* __restrict__ R) {
  int b = blockIdx.x >> 7;
  int row = (blockIdx.x >> 1) & 63;
  int p0 = (blockIdx.x & 1) * 32;
  __shared__ ushort4 s_ti[288];      // [k][lpx]  2304 B
  __shared__ float4 s_tw[288];       //           4608 B
  __shared__ float sv[2048];         // vtab      8192 B
  __shared__ float sbn[256];         //           1024 B
  __shared__ float sRed[512];        // [lpx][16] 2048 B
  int t = threadIdx.x, lane = t & 63, wvx = t >> 6;
  int l15 = lane & 15, quad = lane >> 4;
  int oh = wvx & 1, pxq = wvx >> 1;

  // prologue: taps (4 clamped pixel idx + 4 mask-folded weights per (k,lpx))
  for (int i = t; i < 288; i += 256) {
    int k = i >> 5, p = i & 31;
    int pp = p0 + p;
    float o1 = bf2f(om[(((size_t)(b * 27 + k)) << 12) + row * 64 + pp]);
    float o2 = bf2f(om[(((size_t)(b * 27 + 9 + k)) << 12) + row * 64 + pp]);
    float mv = bf2f(om[(((size_t)(b * 27 + 18 + k)) << 12) + row * 64 + pp]);
    float m = 1.f / (1.f + __expf(-mv));
    float py = (float)(row + k / 3 - 1) + o1;
    float pxf = (float)(pp + (k % 3) - 1) + o2;
    float fy = floorf(py), fx = floorf(pxf);
    int iy = (int)fy, ix = (int)fx;
    float wy1 = py - fy, wy0 = 1.f - wy1;
    float wx1 = pxf - fx, wx0 = 1.f - wx1;
    bool y0ok = (iy >= 0) & (iy < 64), y1ok = (iy >= -1) & (iy < 63);
    bool x0ok = (ix >= 0) & (ix < 64), x1ok = (ix >= -1) & (ix < 63);
    int iy0 = min(max(iy, 0), 63), iy1 = min(max(iy + 1, 0), 63);
    int ix0 = min(max(ix, 0), 63), ix1 = min(max(ix + 1, 0), 63);
    s_ti[i] = make_ushort4((unsigned short)(iy0 * 64 + ix0), (unsigned short)(iy0 * 64 + ix1),
                           (unsigned short)(iy1 * 64 + ix0), (unsigned short)(iy1 * 64 + ix1));
    float4 w;
    w.x = (y0ok && x0ok) ? m * wy0 * wx0 : 0.f;
    w.y = (y0ok && x1ok) ? m * wy0 * wx1 : 0.f;
    w.z = (y1ok && x0ok) ? m * wy1 * wx0 : 0.f;
    w.w = (y1ok && x1ok) ? m * wy1 * wx1 : 0.f;
    s_tw[i] = w;
  }
  // epilogue tables (also behind this one barrier)
  for (int i = t; i < 2048; i += 256) sv[i] = vtab[i];
  if (t < 256) sbn[t] = bntab[t];
  __syncthreads();   // only block-wide barrier before epilogue

  int lpx = pxq * 16 + l15;          // 0..31 (block-local px)
  const unsigned short* xb = xT + (((size_t)b) << 12) * 256;
  const unsigned short* wbase = wt + (size_t)(oh * 64 + l15) * 32 + quad * 8;

  floatx4 acc[4];
#pragma unroll
  for (int i = 0; i < 4; ++i) acc[i] = (floatx4){0.f, 0.f, 0.f, 0.f};

  for (int s3 = 0; s3 < 24; ++s3) {   // k-triplets: s = s3*3 + kk
    int cg = s3 / 3;
    int cb = cg * 32 + quad * 8;
    // issue all 12 tap loads (3 k's) for MLP
    uint4 tr[12];
    float4 tw[3];
#pragma unroll
    for (int kk = 0; kk < 3; ++kk) {
      int k = (s3 % 3) * 3 + kk;
      ushort4 ti = s_ti[(k << 5) + lpx];
      tw[kk] = s_tw[(k << 5) + lpx];
      tr[kk * 4 + 0] = *(const uint4*)&xb[(size_t)ti.x * 256 + cb];
      tr[kk * 4 + 1] = *(const uint4*)&xb[(size_t)ti.y * 256 + cb];
      tr[kk * 4 + 2] = *(const uint4*)&xb[(size_t)ti.z * 256 + cb];
      tr[kk * 4 + 3] = *(const uint4*)&xb[(size_t)ti.w * 256 + cb];
    }
#pragma unroll
    for (int kk = 0; kk < 3; ++kk) {
      int s = s3 * 3 + kk;
      union { uint4 u; short8 s8; } x0, x1, x2, x3;
      x0.u = tr[kk * 4 + 0]; x1.u = tr[kk * 4 + 1];
      x2.u = tr[kk * 4 + 2]; x3.u = tr[kk * 4 + 3];
      float r[8];
#pragma unroll
      for (int j = 0; j < 8; ++j)
        r[j] = tw[kk].x * bf2f((unsigned short)x0.s8[j]) +
               tw[kk].y * bf2f((unsigned short)x1.s8[j]) +
               tw[kk].z * bf2f((unsigned short)x2.s8[j]) +
               tw[kk].w * bf2f((unsigned short)x3.s8[j]);
      union { uint4 u; short8 s8; } bu;
      bu.u = make_uint4(bf16h(r[0]) | (bf16h(r[1]) << 16), bf16h(r[2]) | (bf16h(r[3]) << 16),
                        bf16h(r[4]) | (bf16h(r[5]) << 16), bf16h(r[6]) | (bf16h(r[7]) << 16));
      const unsigned short* wp = wbase + (size_t)s * 4096;   // (s*128)*32
#pragma unroll
      for (int ot = 0; ot < 4; ++ot) {
        short8 af = *(const short8*)&wp[ot * 512];           // (ot*16)*32
        acc[ot] = __builtin_amdgcn_mfma_f32_16x16x32_bf16(af, bu.s8, acc[ot], 0, 0, 0);
      }
    }
  }

  // epilogue: BN+ReLU, vtab reduce over this wave's 64 o, quad butterfly,
  // then pair-reduce the two o-halves through LDS.
  float rpart[16];
#pragma unroll
  for (int i = 0; i < 16; ++i) rpart[i] = 0.f;
#pragma unroll
  for (int ot = 0; ot < 4; ++ot)
#pragma unroll
    for (int r = 0; r < 4; ++r) {
      int o = oh * 64 + ot * 16 + quad * 4 + r;
      float yv = fmaxf(acc[ot][r] * sbn[o] + sbn[128 + o], 0.f);
      const float* vp = &sv[o * 16];
#pragma unroll
      for (int tt = 0; tt < 16; ++tt) rpart[tt] += vp[tt] * yv;
    }
#pragma unroll
  for (int tt = 0; tt < 16; ++tt) {
    rpart[tt] += __shfl_xor(rpart[tt], 16, 64);
    rpart[tt] += __shfl_xor(rpart[tt], 32, 64);
  }
  if (oh == 0) {
#pragma unroll
    for (int j = 0; j < 4; ++j) sRed[lpx * 16 + quad * 4 + j] = rpart[quad * 4 + j];
  }
  __syncthreads();
  if (oh == 1) {
    size_t rbase = ((size_t)((b << 12) + row * 64 + p0 + lpx)) * 16;
#pragma unroll
    for (int j = 0; j < 4; ++j)
      R[rbase + quad * 4 + j] = rpart[quad * 4 + j] + sRed[lpx * 16 + quad * 4 + j];
  }
}

// ---------------------------------------------------------------------------
// K3: upsample+1x1+sigmoid from R maps, LDS-tiled (coalesced R reads).
// ---------------------------------------------------------------------------
__global__ __launch_bounds__(256) void k_upb(
    const float* __restrict__ R, float* __restrict__ out) {
  __shared__ float sR[10 * 10 * 16];   // 6.4 KB
  int b = blockIdx.x >> 6;
  int ty = (blockIdx.x >> 3) & 7, tx = blockIdx.x & 7;
  int Y0 = ty * 16, X0 = tx * 16;
  int ib = (Y0 >> 1) - 1, jb = (X0 >> 1) - 1;
  int t = threadIdx.x;
  const float* Rb = R + (((size_t)b) << 12) * 16;
  for (int idx = t; idx < 1600; idx += 256) {
    int ii = idx / 160, rem = idx - ii * 160;
    int jj = rem >> 4, tt = rem & 15;
    int gi = ib + ii, gj = jb + jj;
    float v = 0.f;
    if (((unsigned)gi < 64u) && ((unsigned)gj < 64u))
      v = Rb[(size_t)(gi * 64 + gj) * 16 + tt];
    sR[idx] = v;
  }
  __syncthreads();
  int X = X0 + (t & 15), Y = Y0 + (t >> 4);
  int li0, wu0, wu1, lj0, wv0, wv1;
  if (Y & 1) { li0 = ((Y - 1) >> 1) - ib; wu0 = 2; wu1 = 0; }
  else       { li0 = (Y / 2 - 1) - ib;    wu0 = 3; wu1 = 1; }
  if (X & 1) { lj0 = ((X - 1) >> 1) - jb; wv0 = 2; wv1 = 0; }
  else       { lj0 = (X / 2 - 1) - jb;    wv0 = 3; wv1 = 1; }
  int li1 = li0 + 1, lj1 = lj0 + 1;
  float s = sR[(li0 * 10 + lj0) * 16 + wu0 * 4 + wv0] +
            sR[(li0 * 10 + lj1) * 16 + wu0 * 4 + wv1] +
            sR[(li1 * 10 + lj0) * 16 + wu1 * 4 + wv0] +
            sR[(li1 * 10 + lj1) * 16 + wu1 * 4 + wv1];
  out[((size_t)b * 128 + Y) * 128 + X] = 1.f / (1.f + __expf(-s));
}

// ---------------------------------------------------------------------------
extern "C" void kernel_launch(void* const* d_in, const int* in_sizes, int n_in,
                              void* d_out, int out_size, void* d_ws, size_t ws_size,
                              hipStream_t stream) {
  const float* x        = (const float*)d_in[0];
  const float* w_dcn    = (const float*)d_in[1];
  const float* b_dcn    = (const float*)d_in[2];
  const float* w_off    = (const float*)d_in[3];
  const float* b_off    = (const float*)d_in[4];
  const float* bn_gamma = (const float*)d_in[5];
  const float* bn_beta  = (const float*)d_in[6];
  const float* bn_mean  = (const float*)d_in[7];
  const float* bn_var   = (const float*)d_in[8];
  const float* w_up     = (const float*)d_in[9];
  const float* w_1x1    = (const float*)d_in[10];
  float* out = (float*)d_out;

  // ws layout in FLOAT units (21.39 MB total):
  float* ws = (float*)d_ws;
  unsigned short* xT     = (unsigned short*)ws;                    // 8388608 ush
  unsigned short* wt_dcn = (unsigned short*)(ws + 4194304);        //  294912 ush
  unsigned short* wt_off = (unsigned short*)(ws + 4341760);        //   73728 ush
  float* vtab            = ws + 4378624;                           //    2048 f
  float* bntab           = ws + 4380672;                           //     256 f
  unsigned short* om     = (unsigned short*)(ws + 4380928);        //  884736 ush
  float* R               = ws + 4823296;                           //  524288 f

  k_prep<<<1152, 256, 0, stream>>>(w_dcn, w_off, b_dcn, bn_gamma, bn_beta,
                                   bn_mean, bn_var, w_up, w_1x1,
                                   wt_dcn, wt_off, vtab, bntab);
  k_xt<<<1024, 256, 0, stream>>>(x, xT);
  k_offconv<<<512, 256, 0, stream>>>(xT, wt_off, b_off, om);
  k_dcn<<<1024, 256, 0, stream>>>(xT, wt_dcn, om, vtab, bntab, R);
  k_upb<<<512, 256, 0, stream>>>(R, out);
}

// Round 10
// 329.927 us; speedup vs baseline: 1.0238x; 1.0238x over previous
//
#include <hip/hip_runtime.h>
#include <math.h>

typedef __attribute__((ext_vector_type(8))) short short8;
typedef __attribute__((ext_vector_type(4))) float floatx4;
typedef __attribute__((ext_vector_type(2))) float floatx2;

__device__ __forceinline__ unsigned short bf16r(float f) {
  union { float f; unsigned int u; } v; v.f = f;
  unsigned int u = v.u;
  return (unsigned short)((u + 0x7fffu + ((u >> 16) & 1u)) >> 16);
}
__device__ __forceinline__ float bf2f(unsigned int u) {
  union { unsigned int u; float f; } v; v.u = u << 16; return v.f;
}
// unpack 2 bf16 (one dword) -> 2 fp32
__device__ __forceinline__ floatx2 bfpair(unsigned int u) {
  union { unsigned int u; float f; } lo, hi;
  lo.u = u << 16; hi.u = u & 0xffff0000u;
  return (floatx2){lo.f, hi.f};
}
// pack 2 fp32 -> 2 bf16 in one dword (round-half-up) via v_perm_b32
__device__ __forceinline__ unsigned int packpair(floatx2 v) {
  union { float f; unsigned int u; } a, b;
  a.f = v[0]; b.f = v[1];
  return __builtin_amdgcn_perm(b.u + 0x8000u, a.u + 0x8000u, 0x07060302u);
}
// async global->LDS DMA, 16B/lane; LDS dst = wave-uniform base + lane*16
__device__ __forceinline__ void glds16(const void* g, void* l) {
  __builtin_amdgcn_global_load_lds(
      (const __attribute__((address_space(1))) unsigned int*)g,
      (__attribute__((address_space(3))) unsigned int*)l, 16, 0, 0);
}

// ---------------------------------------------------------------------------
// K0 (merged prep + xT):
//  blocks [0,1024):   x fp32 NCHW -> xT bf16 [b][pixel][c]
//  blocks [1024,2176): weights -> bf16 + fused tables.
//  wt_dcn is stored SWIZZLED so the k_dcn LDS image is bank-conflict-free:
//    physical group g = (q + ((o&15)>>1)) & 3   (q = logical cc>>3)
// ---------------------------------------------------------------------------
__global__ __launch_bounds__(256) void k_pre(
    const float* __restrict__ x, const float* __restrict__ w_dcn,
    const float* __restrict__ w_off, const float* __restrict__ b_dcn,
    const float* __restrict__ bn_g, const float* __restrict__ bn_b,
    const float* __restrict__ bn_m, const float* __restrict__ bn_v,
    const float* __restrict__ w_up, const float* __restrict__ w1x1,
    unsigned short* __restrict__ xT, unsigned short* __restrict__ wt_dcn,
    unsigned short* __restrict__ wt_off,
    float* __restrict__ vtab, float* __restrict__ bntab) {
  __shared__ unsigned short sx[32 * 264];
  int t = threadIdx.x;
  if (blockIdx.x < 1024) {
    int b = blockIdx.x >> 7, px0 = (blockIdx.x & 127) * 32;
    int pg = (t & 7) * 4, cg = t >> 3;
    const float* xsrc = x + (((size_t)(b * 256 + cg * 8)) << 12) + px0 + pg;
#pragma unroll
    for (int cc = 0; cc < 8; ++cc) {
      float4 v = *(const float4*)&xsrc[(size_t)cc << 12];
      int c = cg * 8 + cc;
      sx[(pg + 0) * 264 + c] = bf16r(v.x);
      sx[(pg + 1) * 264 + c] = bf16r(v.y);
      sx[(pg + 2) * 264 + c] = bf16r(v.z);
      sx[(pg + 3) * 264 + c] = bf16r(v.w);
    }
    __syncthreads();
#pragma unroll
    for (int j = 0; j < 4; ++j) {
      int unit = t + j * 256;
      int p = unit >> 5, chunk = unit & 31;
      uint4 v = *(const uint4*)&sx[p * 264 + chunk * 8];
      *(uint4*)&xT[((size_t)((b << 12) + px0 + p)) * 256 + chunk * 8] = v;
    }
    return;
  }
  int e = (blockIdx.x - 1024) * 256 + t;
  if (e < 294912) {            // wt_dcn, swizzled
    int j = e & 7, g = (e >> 3) & 3, o = (e >> 5) & 127, s = e >> 12;
    int q = (g - ((o >> 1) & 3)) & 3;
    int k = s % 9, cgp = s / 9, c = cgp * 32 + q * 8 + j;
    wt_dcn[e] = bf16r(w_dcn[(o * 256 + c) * 9 + k]);
  }
  if (e < 73728) {             // wt_off, linear (read from global, no LDS)
    int cc = e & 31, oc = (e >> 5) & 31, s = e >> 10;
    int k = s % 9, cgp = s / 9, c = cgp * 32 + cc;
    wt_off[e] = (oc < 27) ? bf16r(w_off[(oc * 256 + c) * 9 + k]) : (unsigned short)0;
  }
  if (e < 2048) {
    int o = e >> 4;
    vtab[e] = w1x1[o] * w_up[e];
  }
  if (e < 128) {
    float g = bn_g[e] * rsqrtf(bn_v[e] + 1e-5f);
    bntab[e] = g;
    bntab[128 + e] = (b_dcn[e] - bn_m[e]) * g + bn_b[e];
  }
}

// ---------------------------------------------------------------------------
// K1: offset conv via MFMA, zero LDS / zero barriers, batched loads (MLP).
// ---------------------------------------------------------------------------
__global__ __launch_bounds__(256, 2) void k_offconv(
    const unsigned short* __restrict__ xT, const unsigned short* __restrict__ wt_off,
    const float* __restrict__ b_off, unsigned short* __restrict__ om) {
  int b = blockIdx.x >> 6, row = blockIdx.x & 63;
  int t = threadIdx.x, lane = t & 63, wvx = t >> 6;
  int l15 = lane & 15, quad = lane >> 4;
  int xcol = wvx * 16 + l15;
  const unsigned short* xb = xT + (((size_t)b) << 12) * 256;
  const short8 zz = {0, 0, 0, 0, 0, 0, 0, 0};

  int pixk[9]; bool vk[9];
#pragma unroll
  for (int k = 0; k < 9; ++k) {
    int yy = row + k / 3 - 1, xx = xcol + k % 3 - 1;
    vk[k] = ((unsigned)yy < 64u) & ((unsigned)xx < 64u);
    pixk[k] = vk[k] ? (yy * 64 + xx) : 0;
  }

  floatx4 acc[2];
  acc[0] = (floatx4){0.f, 0.f, 0.f, 0.f};
  acc[1] = (floatx4){0.f, 0.f, 0.f, 0.f};

  for (int cg = 0; cg < 8; ++cg) {
    int cb = cg * 32 + quad * 8;
    short8 bx[9];
#pragma unroll
    for (int k = 0; k < 9; ++k) {
      short8 v = *(const short8*)&xb[(size_t)pixk[k] * 256 + cb];
      bx[k] = vk[k] ? v : zz;
    }
#pragma unroll
    for (int k = 0; k < 9; ++k) {
      const unsigned short* wp = wt_off + (size_t)(cg * 9 + k) * 1024;
      short8 a0 = *(const short8*)&wp[l15 * 32 + quad * 8];
      short8 a1 = *(const short8*)&wp[(16 + l15) * 32 + quad * 8];
      acc[0] = __builtin_amdgcn_mfma_f32_16x16x32_bf16(a0, bx[k], acc[0], 0, 0, 0);
      acc[1] = __builtin_amdgcn_mfma_f32_16x16x32_bf16(a1, bx[k], acc[1], 0, 0, 0);
    }
  }
#pragma unroll
  for (int ot = 0; ot < 2; ++ot)
#pragma unroll
    for (int r = 0; r < 4; ++r) {
      int o = ot * 16 + quad * 4 + r;
      if (o < 27)
        om[(((size_t)(b * 27 + o)) << 12) + row * 64 + xcol] = bf16r(acc[ot][r] + b_off[o]);
    }
}

// ---------------------------------------------------------------------------
// K2: DCNv2 via MFMA + fused BN/ReLU + fused (upsample x 1x1) -> R.
// 512-thread blocks (8 waves, 128px x 128o), grid 256 -> 16 waves/CU.
// R7 phase structure: dbuf W via glds, 1 barrier/phase, in-loop tap refill.
// W LDS image is swizzle-laid (see k_pre) -> conflict-free ds_read_b128.
// ---------------------------------------------------------------------------
__global__ __launch_bounds__(512, 4) void k_dcn(
    const unsigned short* __restrict__ xT, const unsigned short* __restrict__ wt,
    const unsigned short* __restrict__ om, const float* __restrict__ vtab,
    const float* __restrict__ bntab, float* __restrict__ R) {
  int b = blockIdx.x >> 5;
  int p0 = (blockIdx.x & 31) * 128;
  __shared__ unsigned short sW[2 * 12288];   // 49152 B
  __shared__ ushort4 s_ti[1152];             //  9216 B
  __shared__ float4 s_tw[1152];              // 18432 B   (total 76800 <= 80K)
  int t = threadIdx.x, lane = t & 63, wvx = t >> 6;
  int l15 = lane & 15, quad = lane >> 4;
  int swz = ((quad + ((l15 >> 1) & 3)) & 3) * 8;   // conflict-free A-frag group

  // prologue: taps (4 clamped pixel idx + 4 mask-folded weights per (k,px))
  for (int i = t; i < 1152; i += 512) {
    int k = i >> 7, p = i & 127;
    int pp = p0 + p;
    int gy = pp >> 6, gx = pp & 63;
    float o1 = bf2f(om[(((size_t)(b * 27 + k)) << 12) + pp]);
    float o2 = bf2f(om[(((size_t)(b * 27 + 9 + k)) << 12) + pp]);
    float mv = bf2f(om[(((size_t)(b * 27 + 18 + k)) << 12) + pp]);
    float m = 1.f / (1.f + __expf(-mv));
    float py = (float)(gy + k / 3 - 1) + o1;
    float pxf = (float)(gx + (k % 3) - 1) + o2;
    float fy = floorf(py), fx = floorf(pxf);
    int iy = (int)fy, ix = (int)fx;
    float wy1 = py - fy, wy0 = 1.f - wy1;
    float wx1 = pxf - fx, wx0 = 1.f - wx1;
    bool y0ok = (iy >= 0) & (iy < 64), y1ok = (iy >= -1) & (iy < 63);
    bool x0ok = (ix >= 0) & (ix < 64), x1ok = (ix >= -1) & (ix < 63);
    int iy0 = min(max(iy, 0), 63), iy1 = min(max(iy + 1, 0), 63);
    int ix0 = min(max(ix, 0), 63), ix1 = min(max(ix + 1, 0), 63);
    s_ti[i] = make_ushort4((unsigned short)(iy0 * 64 + ix0), (unsigned short)(iy0 * 64 + ix1),
                           (unsigned short)(iy1 * 64 + ix0), (unsigned short)(iy1 * 64 + ix1));
    float4 w;
    w.x = (y0ok && x0ok) ? m * wy0 * wx0 : 0.f;
    w.y = (y0ok && x1ok) ? m * wy0 * wx1 : 0.f;
    w.z = (y1ok && x0ok) ? m * wy1 * wx0 : 0.f;
    w.w = (y1ok && x1ok) ? m * wy1 * wx1 : 0.f;
    s_tw[i] = w;
  }
  __syncthreads();   // s_ti/s_tw ready (read-only hereafter)

  int lpx = wvx * 16 + l15;                 // 0..127 block-local pixel
  const unsigned short* xb = xT + (((size_t)b) << 12) * 256;

  floatx4 acc[8];
#pragma unroll
  for (int i = 0; i < 8; ++i) acc[i] = (floatx4){0.f, 0.f, 0.f, 0.f};

  uint4 traw[12];   // current-phase tap data, refilled in-loop (R7 pattern)

#define ISSUE_TAPS(PH) { \
    int cb_ = ((PH) / 3) * 32 + quad * 8; \
    _Pragma("unroll") \
    for (int kk_ = 0; kk_ < 3; ++kk_) { \
      int k_ = ((PH) % 3) * 3 + kk_; \
      ushort4 ti_ = s_ti[(k_ << 7) + lpx]; \
      traw[kk_ * 4 + 0] = *(const uint4*)&xb[(size_t)ti_.x * 256 + cb_]; \
      traw[kk_ * 4 + 1] = *(const uint4*)&xb[(size_t)ti_.y * 256 + cb_]; \
      traw[kk_ * 4 + 2] = *(const uint4*)&xb[(size_t)ti_.z * 256 + cb_]; \
      traw[kk_ * 4 + 3] = *(const uint4*)&xb[(size_t)ti_.w * 256 + cb_]; \
    } }

#define GLDS_W(PH) { \
    const unsigned short* ws_ = wt + (size_t)(PH) * 12288; \
    unsigned short* dst_ = sW + ((PH) & 1) * 12288; \
    _Pragma("unroll") \
    for (int i_ = 0; i_ < 3; ++i_) { \
      int blk_ = wvx * 3 + i_; \
      glds16(ws_ + (size_t)blk_ * 512 + lane * 8, dst_ + blk_ * 512); \
    } }

  ISSUE_TAPS(0);
  GLDS_W(0);
  __syncthreads();   // phase-0 W complete; taps landing in regs

  for (int phase = 0; phase < 24; ++phase) {
    if (phase < 23) GLDS_W(phase + 1);
    const unsigned short* buf = sW + (phase & 1) * 12288;
    int nphase = phase + 1;
    int ncb = (nphase / 3) * 32 + quad * 8;
#pragma unroll
    for (int kk = 0; kk < 3; ++kk) {
      int k = (phase % 3) * 3 + kk;
      float4 tw = s_tw[(k << 7) + lpx];
      uint4 q0 = traw[kk * 4 + 0], q1 = traw[kk * 4 + 1];
      uint4 q2 = traw[kk * 4 + 2], q3 = traw[kk * 4 + 3];
      if (phase < 23) {   // refill slots for next phase (consumed above)
        int nk = (nphase % 3) * 3 + kk;
        ushort4 ti = s_ti[(nk << 7) + lpx];
        traw[kk * 4 + 0] = *(const uint4*)&xb[(size_t)ti.x * 256 + ncb];
        traw[kk * 4 + 1] = *(const uint4*)&xb[(size_t)ti.y * 256 + ncb];
        traw[kk * 4 + 2] = *(const uint4*)&xb[(size_t)ti.z * 256 + ncb];
        traw[kk * 4 + 3] = *(const uint4*)&xb[(size_t)ti.w * 256 + ncb];
      }
      // 4-tap sample, 2 channels per dword (packed-fp32-friendly)
      floatx2 r2[4];
      const unsigned int* u0 = (const unsigned int*)&q0;
      const unsigned int* u1 = (const unsigned int*)&q1;
      const unsigned int* u2 = (const unsigned int*)&q2;
      const unsigned int* u3 = (const unsigned int*)&q3;
#pragma unroll
      for (int j = 0; j < 4; ++j)
        r2[j] = tw.x * bfpair(u0[j]) + tw.y * bfpair(u1[j]) +
                tw.z * bfpair(u2[j]) + tw.w * bfpair(u3[j]);
      union { uint4 u; short8 s8; } bu;
      bu.u = make_uint4(packpair(r2[0]), packpair(r2[1]), packpair(r2[2]), packpair(r2[3]));
#pragma unroll
      for (int ot = 0; ot < 8; ++ot) {
        short8 af = *(const short8*)&buf[(kk * 128 + ot * 16 + l15) * 32 + swz];
        acc[ot] = __builtin_amdgcn_mfma_f32_16x16x32_bf16(af, bu.s8, acc[ot], 0, 0, 0);
      }
    }
    __syncthreads();  // drains glds(next) + all waves done reading buf
  }

  // epilogue: BN+ReLU then R_t[px] = sum_o v[o][t]*yv, reduced over quads
  float* sv = (float*)sW;          // reuse sW: 2048 vtab + 256 bn
  float* sbn = sv + 2048;
  for (int i = t; i < 2048; i += 512) sv[i] = vtab[i];
  if (t < 256) sbn[t] = bntab[t];
  __syncthreads();

  float rpart[16];
#pragma unroll
  for (int i = 0; i < 16; ++i) rpart[i] = 0.f;
#pragma unroll
  for (int ot = 0; ot < 8; ++ot)
#pragma unroll
    for (int r = 0; r < 4; ++r) {
      int o = ot * 16 + quad * 4 + r;
      float yv = fmaxf(acc[ot][r] * sbn[o] + sbn[128 + o], 0.f);
      const float* vp = &sv[o * 16];
#pragma unroll
      for (int tt = 0; tt < 16; ++tt) rpart[tt] += vp[tt] * yv;
    }
#pragma unroll
  for (int tt = 0; tt < 16; ++tt) {
    rpart[tt] += __shfl_xor(rpart[tt], 16, 64);
    rpart[tt] += __shfl_xor(rpart[tt], 32, 64);
  }
  size_t rbase = ((size_t)((b << 12) + p0 + lpx)) * 16;
#pragma unroll
  for (int j = 0; j < 4; ++j) R[rbase + quad * 4 + j] = rpart[quad * 4 + j];
}

// ---------------------------------------------------------------------------
// K3: upsample+1x1+sigmoid from R maps, LDS-tiled (coalesced R reads).
// ---------------------------------------------------------------------------
__global__ __launch_bounds__(256) void k_upb(
    const float* __restrict__ R, float* __restrict__ out) {
  __shared__ float sR[10 * 10 * 16];   // 6.4 KB
  int b = blockIdx.x >> 6;
  int ty = (blockIdx.x >> 3) & 7, tx = blockIdx.x & 7;
  int Y0 = ty * 16, X0 = tx * 16;
  int ib = (Y0 >> 1) - 1, jb = (X0 >> 1) - 1;
  int t = threadIdx.x;
  const float* Rb = R + (((size_t)b) << 12) * 16;
  for (int idx = t; idx < 1600; idx += 256) {
    int ii = idx / 160, rem = idx - ii * 160;
    int jj = rem >> 4, tt = rem & 15;
    int gi = ib + ii, gj = jb + jj;
    float v = 0.f;
    if (((unsigned)gi < 64u) && ((unsigned)gj < 64u))
      v = Rb[(size_t)(gi * 64 + gj) * 16 + tt];
    sR[idx] = v;
  }
  __syncthreads();
  int X = X0 + (t & 15), Y = Y0 + (t >> 4);
  int li0, wu0, wu1, lj0, wv0, wv1;
  if (Y & 1) { li0 = ((Y - 1) >> 1) - ib; wu0 = 2; wu1 = 0; }
  else       { li0 = (Y / 2 - 1) - ib;    wu0 = 3; wu1 = 1; }
  if (X & 1) { lj0 = ((X - 1) >> 1) - jb; wv0 = 2; wv1 = 0; }
  else       { lj0 = (X / 2 - 1) - jb;    wv0 = 3; wv1 = 1; }
  int li1 = li0 + 1, lj1 = lj0 + 1;
  float s = sR[(li0 * 10 + lj0) * 16 + wu0 * 4 + wv0] +
            sR[(li0 * 10 + lj1) * 16 + wu0 * 4 + wv1] +
            sR[(li1 * 10 + lj0) * 16 + wu1 * 4 + wv0] +
            sR[(li1 * 10 + lj1) * 16 + wu1 * 4 + wv1];
  out[((size_t)b * 128 + Y) * 128 + X] = 1.f / (1.f + __expf(-s));
}

// ---------------------------------------------------------------------------
extern "C" void kernel_launch(void* const* d_in, const int* in_sizes, int n_in,
                              void* d_out, int out_size, void* d_ws, size_t ws_size,
                              hipStream_t stream) {
  const float* x        = (const float*)d_in[0];
  const float* w_dcn    = (const float*)d_in[1];
  const float* b_dcn    = (const float*)d_in[2];
  const float* w_off    = (const float*)d_in[3];
  const float* b_off    = (const float*)d_in[4];
  const float* bn_gamma = (const float*)d_in[5];
  const float* bn_beta  = (const float*)d_in[6];
  const float* bn_mean  = (const float*)d_in[7];
  const float* bn_var   = (const float*)d_in[8];
  const float* w_up     = (const float*)d_in[9];
  const float* w_1x1    = (const float*)d_in[10];
  float* out = (float*)d_out;

  // ws layout in FLOAT units (21.39 MB total):
  float* ws = (float*)d_ws;
  unsigned short* xT     = (unsigned short*)ws;                    // 8388608 ush
  unsigned short* wt_dcn = (unsigned short*)(ws + 4194304);        //  294912 ush
  unsigned short* wt_off = (unsigned short*)(ws + 4341760);        //   73728 ush
  float* vtab            = ws + 4378624;                           //    2048 f
  float* bntab           = ws + 4380672;                           //     256 f
  unsigned short* om     = (unsigned short*)(ws + 4380928);        //  884736 ush
  float* R               = ws + 4823296;                           //  524288 f

  k_pre<<<2176, 256, 0, stream>>>(x, w_dcn, w_off, b_dcn, bn_gamma, bn_beta,
                                  bn_mean, bn_var, w_up, w_1x1,
                                  xT, wt_dcn, wt_off, vtab, bntab);
  k_offconv<<<512, 256, 0, stream>>>(xT, wt_off, b_off, om);
  k_dcn<<<256, 512, 0, stream>>>(xT, wt_dcn, om, vtab, bntab, R);
  k_upb<<<512, 256, 0, stream>>>(R, out);
}

// Round 11
// 227.762 us; speedup vs baseline: 1.4831x; 1.4486x over previous
//
#include <hip/hip_runtime.h>
#include <math.h>

typedef __attribute__((ext_vector_type(8))) short short8;
typedef __attribute__((ext_vector_type(4))) float floatx4;
typedef __attribute__((ext_vector_type(2))) float floatx2;

__device__ __forceinline__ unsigned short bf16r(float f) {
  union { float f; unsigned int u; } v; v.f = f;
  unsigned int u = v.u;
  return (unsigned short)((u + 0x7fffu + ((u >> 16) & 1u)) >> 16);
}
__device__ __forceinline__ float bf2f(unsigned int u) {
  union { unsigned int u; float f; } v; v.u = u << 16; return v.f;
}
// unpack 2 bf16 (one dword) -> 2 fp32
__device__ __forceinline__ floatx2 bfpair(unsigned int u) {
  union { unsigned int u; float f; } lo, hi;
  lo.u = u << 16; hi.u = u & 0xffff0000u;
  return (floatx2){lo.f, hi.f};
}
// pack 2 fp32 -> 2 bf16 in one dword (round-half-up) via v_perm_b32
__device__ __forceinline__ unsigned int packpair(floatx2 v) {
  union { float f; unsigned int u; } a, b;
  a.f = v[0]; b.f = v[1];
  return __builtin_amdgcn_perm(b.u + 0x8000u, a.u + 0x8000u, 0x07060302u);
}
// async global->LDS DMA, 16B/lane; LDS dst = wave-uniform base + lane*16
__device__ __forceinline__ void glds16(const void* g, void* l) {
  __builtin_amdgcn_global_load_lds(
      (const __attribute__((address_space(1))) unsigned int*)g,
      (__attribute__((address_space(3))) unsigned int*)l, 16, 0, 0);
}

// ---------------------------------------------------------------------------
// K0 (merged prep + xT):
//  blocks [0,1024):    x fp32 NCHW -> xT bf16 [b][pixel][c]
//  blocks [1024,2176): weights -> bf16 + fused tables.
//  wt_dcn stored SWIZZLED: physical 8-ch group g = (q + ((o>>1)&3)) & 3, so
//  k_dcn's A-frag ds_read_b128 is <=2-way bank-aliased (free).
// ---------------------------------------------------------------------------
__global__ __launch_bounds__(256) void k_pre(
    const float* __restrict__ x, const float* __restrict__ w_dcn,
    const float* __restrict__ w_off, const float* __restrict__ b_dcn,
    const float* __restrict__ bn_g, const float* __restrict__ bn_b,
    const float* __restrict__ bn_m, const float* __restrict__ bn_v,
    const float* __restrict__ w_up, const float* __restrict__ w1x1,
    unsigned short* __restrict__ xT, unsigned short* __restrict__ wt_dcn,
    unsigned short* __restrict__ wt_off,
    float* __restrict__ vtab, float* __restrict__ bntab) {
  __shared__ unsigned short sx[32 * 264];
  int t = threadIdx.x;
  if (blockIdx.x < 1024) {
    int b = blockIdx.x >> 7, px0 = (blockIdx.x & 127) * 32;
    int pg = (t & 7) * 4, cg = t >> 3;
#pragma unroll
    for (int cc = 0; cc < 8; ++cc) {
      const float* xsrc = x + (((size_t)(b * 256 + cg * 8 + cc)) << 12) + px0 + pg;
      float4 v = *(const float4*)xsrc;
      int c = cg * 8 + cc;
      sx[(pg + 0) * 264 + c] = bf16r(v.x);
      sx[(pg + 1) * 264 + c] = bf16r(v.y);
      sx[(pg + 2) * 264 + c] = bf16r(v.z);
      sx[(pg + 3) * 264 + c] = bf16r(v.w);
    }
    __syncthreads();
#pragma unroll
    for (int j = 0; j < 4; ++j) {
      int unit = t + j * 256;
      int p = unit >> 5, chunk = unit & 31;
      uint4 v = *(const uint4*)&sx[p * 264 + chunk * 8];
      *(uint4*)&xT[((size_t)((b << 12) + px0 + p)) * 256 + chunk * 8] = v;
    }
    return;
  }
  int e = (blockIdx.x - 1024) * 256 + t;
  if (e < 294912) {            // wt_dcn, swizzled groups
    int j = e & 7, g = (e >> 3) & 3, o = (e >> 5) & 127, s = e >> 12;
    int q = (g - ((o >> 1) & 3)) & 3;
    int k = s % 9, cgp = s / 9, c = cgp * 32 + q * 8 + j;
    wt_dcn[e] = bf16r(w_dcn[(o * 256 + c) * 9 + k]);
  }
  if (e < 73728) {             // wt_off, linear
    int cc = e & 31, oc = (e >> 5) & 31, s = e >> 10;
    int k = s % 9, cgp = s / 9, c = cgp * 32 + cc;
    wt_off[e] = (oc < 27) ? bf16r(w_off[(oc * 256 + c) * 9 + k]) : (unsigned short)0;
  }
  if (e < 2048) {
    int o = e >> 4;
    vtab[e] = w1x1[o] * w_up[e];
  }
  if (e < 128) {
    float g = bn_g[e] * rsqrtf(bn_v[e] + 1e-5f);
    bntab[e] = g;
    bntab[128 + e] = (b_dcn[e] - bn_m[e]) * g + bn_b[e];
  }
}

// ---------------------------------------------------------------------------
// K1: offset conv via MFMA, zero LDS / zero barriers, batched loads (MLP).
// ---------------------------------------------------------------------------
__global__ __launch_bounds__(256, 2) void k_offconv(
    const unsigned short* __restrict__ xT, const unsigned short* __restrict__ wt_off,
    const float* __restrict__ b_off, unsigned short* __restrict__ om) {
  int b = blockIdx.x >> 6, row = blockIdx.x & 63;
  int t = threadIdx.x, lane = t & 63, wvx = t >> 6;
  int l15 = lane & 15, quad = lane >> 4;
  int xcol = wvx * 16 + l15;
  const unsigned short* xb = xT + (((size_t)b) << 12) * 256;
  const short8 zz = {0, 0, 0, 0, 0, 0, 0, 0};

  int pixk[9]; bool vk[9];
#pragma unroll
  for (int k = 0; k < 9; ++k) {
    int yy = row + k / 3 - 1, xx = xcol + k % 3 - 1;
    vk[k] = ((unsigned)yy < 64u) & ((unsigned)xx < 64u);
    pixk[k] = vk[k] ? (yy * 64 + xx) : 0;
  }

  floatx4 acc[2];
  acc[0] = (floatx4){0.f, 0.f, 0.f, 0.f};
  acc[1] = (floatx4){0.f, 0.f, 0.f, 0.f};

  for (int cg = 0; cg < 8; ++cg) {
    int cb = cg * 32 + quad * 8;
    short8 bx[9];
#pragma unroll
    for (int k = 0; k < 9; ++k) {
      short8 v = *(const short8*)&xb[(size_t)pixk[k] * 256 + cb];
      bx[k] = vk[k] ? v : zz;
    }
#pragma unroll
    for (int k = 0; k < 9; ++k) {
      const unsigned short* wp = wt_off + (size_t)(cg * 9 + k) * 1024;
      short8 a0 = *(const short8*)&wp[l15 * 32 + quad * 8];
      short8 a1 = *(const short8*)&wp[(16 + l15) * 32 + quad * 8];
      acc[0] = __builtin_amdgcn_mfma_f32_16x16x32_bf16(a0, bx[k], acc[0], 0, 0, 0);
      acc[1] = __builtin_amdgcn_mfma_f32_16x16x32_bf16(a1, bx[k], acc[1], 0, 0, 0);
    }
  }
#pragma unroll
  for (int ot = 0; ot < 2; ++ot)
#pragma unroll
    for (int r = 0; r < 4; ++r) {
      int o = ot * 16 + quad * 4 + r;
      if (o < 27)
        om[(((size_t)(b * 27 + o)) << 12) + row * 64 + xcol] = bf16r(acc[ot][r] + b_off[o]);
    }
}

// ---------------------------------------------------------------------------
// K2: DCNv2 via MFMA + fused BN/ReLU + fused (upsample x 1x1) -> R.
// EXACT R7 skeleton (256 thr, grid 512, dbuf W via glds, 1 barrier/phase,
// in-loop tap refill) + swizzled W reads + packed sampling math.
// ---------------------------------------------------------------------------
__global__ __launch_bounds__(256, 2) void k_dcn(
    const unsigned short* __restrict__ xT, const unsigned short* __restrict__ wt,
    const unsigned short* __restrict__ om, const float* __restrict__ vtab,
    const float* __restrict__ bntab, float* __restrict__ R) {
  int b = blockIdx.x >> 6, row = blockIdx.x & 63;
  __shared__ unsigned short sW[2 * 12288];   // 49152 B
  __shared__ ushort4 s_ti[576];              //  4608 B
  __shared__ float4 s_tw[576];               //  9216 B  (total 62976)
  int t = threadIdx.x, lane = t & 63, wvx = t >> 6;
  int l15 = lane & 15, quad = lane >> 4;
  int swz = ((quad + ((l15 >> 1) & 3)) & 3) * 8;   // matches k_pre swizzle

  // prologue: taps = 4 clamped pixel indices + 4 mask-folded weights per (k,px)
  for (int i = t; i < 576; i += 256) {
    int k = i >> 6, p = i & 63;
    float o1 = bf2f(om[(((size_t)(b * 27 + k)) << 12) + row * 64 + p]);
    float o2 = bf2f(om[(((size_t)(b * 27 + 9 + k)) << 12) + row * 64 + p]);
    float mv = bf2f(om[(((size_t)(b * 27 + 18 + k)) << 12) + row * 64 + p]);
    float m = 1.f / (1.f + __expf(-mv));
    float py = (float)(row + k / 3 - 1) + o1;
    float pxf = (float)(p + (k % 3) - 1) + o2;
    float fy = floorf(py), fx = floorf(pxf);
    int iy = (int)fy, ix = (int)fx;
    float wy1 = py - fy, wy0 = 1.f - wy1;
    float wx1 = pxf - fx, wx0 = 1.f - wx1;
    bool y0ok = (iy >= 0) & (iy < 64), y1ok = (iy >= -1) & (iy < 63);
    bool x0ok = (ix >= 0) & (ix < 64), x1ok = (ix >= -1) & (ix < 63);
    int iy0 = min(max(iy, 0), 63), iy1 = min(max(iy + 1, 0), 63);
    int ix0 = min(max(ix, 0), 63), ix1 = min(max(ix + 1, 0), 63);
    s_ti[i] = make_ushort4((unsigned short)(iy0 * 64 + ix0), (unsigned short)(iy0 * 64 + ix1),
                           (unsigned short)(iy1 * 64 + ix0), (unsigned short)(iy1 * 64 + ix1));
    float4 w;
    w.x = (y0ok && x0ok) ? m * wy0 * wx0 : 0.f;
    w.y = (y0ok && x1ok) ? m * wy0 * wx1 : 0.f;
    w.z = (y1ok && x0ok) ? m * wy1 * wx0 : 0.f;
    w.w = (y1ok && x1ok) ? m * wy1 * wx1 : 0.f;
    s_tw[i] = w;
  }
  __syncthreads();   // s_ti/s_tw ready (read-only hereafter)

  int px = wvx * 16 + l15;
  const unsigned short* xb = xT + (((size_t)b) << 12) * 256;

  floatx4 acc[8];
#pragma unroll
  for (int i = 0; i < 8; ++i) acc[i] = (floatx4){0.f, 0.f, 0.f, 0.f};

  // tap raw data for current phase (refilled in-loop, R7 pattern)
  uint4 traw[12];
  {
    int cbase = quad * 8;                       // phase 0: cg=0
#pragma unroll
    for (int kk = 0; kk < 3; ++kk) {
      ushort4 ti = s_ti[(kk << 6) + px];        // phase 0: k = kk
      traw[kk * 4 + 0] = *(const uint4*)&xb[(size_t)ti.x * 256 + cbase];
      traw[kk * 4 + 1] = *(const uint4*)&xb[(size_t)ti.y * 256 + cbase];
      traw[kk * 4 + 2] = *(const uint4*)&xb[(size_t)ti.z * 256 + cbase];
      traw[kk * 4 + 3] = *(const uint4*)&xb[(size_t)ti.w * 256 + cbase];
    }
  }
  {  // glds W(phase 0) -> buf 0
    const unsigned short* wsrc = wt;
#pragma unroll
    for (int i = 0; i < 6; ++i) {
      int blk = wvx * 6 + i;
      glds16(wsrc + (size_t)blk * 512 + lane * 8, &sW[blk * 512]);
    }
  }
  __syncthreads();   // buf0 complete (vmcnt drain) + taps in regs

  for (int phase = 0; phase < 24; ++phase) {
    unsigned short* buf = sW + (phase & 1) * 12288;
    unsigned short* nbuf = sW + ((phase + 1) & 1) * 12288;
    if (phase < 23) {
      const unsigned short* wsrc = wt + (size_t)(phase + 1) * 12288;
#pragma unroll
      for (int i = 0; i < 6; ++i) {
        int blk = wvx * 6 + i;
        glds16(wsrc + (size_t)blk * 512 + lane * 8, &nbuf[blk * 512]);
      }
    }
    int nphase = phase + 1;
    int ncbase = (nphase / 3) * 32 + quad * 8;

#pragma unroll
    for (int kk = 0; kk < 3; ++kk) {
      int k = (phase % 3) * 3 + kk;
      float4 tw = s_tw[(k << 6) + px];
      uint4 q0 = traw[kk * 4 + 0], q1 = traw[kk * 4 + 1];
      uint4 q2 = traw[kk * 4 + 2], q3 = traw[kk * 4 + 3];
      if (phase < 23) {   // refill slots for next phase (consumed above)
        int nk = (nphase % 3) * 3 + kk;
        ushort4 ti = s_ti[(nk << 6) + px];
        traw[kk * 4 + 0] = *(const uint4*)&xb[(size_t)ti.x * 256 + ncbase];
        traw[kk * 4 + 1] = *(const uint4*)&xb[(size_t)ti.y * 256 + ncbase];
        traw[kk * 4 + 2] = *(const uint4*)&xb[(size_t)ti.z * 256 + ncbase];
        traw[kk * 4 + 3] = *(const uint4*)&xb[(size_t)ti.w * 256 + ncbase];
      }
      // 4-tap sample, 2 channels per dword (packed math + perm pack)
      floatx2 r2[4];
      const unsigned int* u0 = (const unsigned int*)&q0;
      const unsigned int* u1 = (const unsigned int*)&q1;
      const unsigned int* u2 = (const unsigned int*)&q2;
      const unsigned int* u3 = (const unsigned int*)&q3;
#pragma unroll
      for (int j = 0; j < 4; ++j)
        r2[j] = tw.x * bfpair(u0[j]) + tw.y * bfpair(u1[j]) +
                tw.z * bfpair(u2[j]) + tw.w * bfpair(u3[j]);
      union { uint4 u; short8 s8; } bu;
      bu.u = make_uint4(packpair(r2[0]), packpair(r2[1]), packpair(r2[2]), packpair(r2[3]));
#pragma unroll
      for (int ot = 0; ot < 8; ++ot) {
        short8 af = *(const short8*)&buf[(kk * 128 + ot * 16 + l15) * 32 + swz];
        acc[ot] = __builtin_amdgcn_mfma_f32_16x16x32_bf16(af, bu.s8, acc[ot], 0, 0, 0);
      }
    }
    __syncthreads();  // drains glds(next) + all waves done reading buf
  }

  // epilogue: BN+ReLU then R_t[px] = sum_o v[o][t]*yv, reduced over quads
  float* sv = (float*)sW;          // reuse sW: 2048 vtab + 256 bn
  float* sbn = sv + 2048;
  for (int i = t; i < 2048; i += 256) sv[i] = vtab[i];
  if (t < 256) sbn[t] = bntab[t];
  __syncthreads();

  float rpart[16];
#pragma unroll
  for (int i = 0; i < 16; ++i) rpart[i] = 0.f;
#pragma unroll
  for (int ot = 0; ot < 8; ++ot)
#pragma unroll
    for (int r = 0; r < 4; ++r) {
      int o = ot * 16 + quad * 4 + r;
      float yv = fmaxf(acc[ot][r] * sbn[o] + sbn[128 + o], 0.f);
      const float* vp = &sv[o * 16];
#pragma unroll
      for (int tt = 0; tt < 16; ++tt) rpart[tt] += vp[tt] * yv;
    }
#pragma unroll
  for (int tt = 0; tt < 16; ++tt) {
    rpart[tt] += __shfl_xor(rpart[tt], 16, 64);
    rpart[tt] += __shfl_xor(rpart[tt], 32, 64);
  }
  size_t rbase = ((size_t)((b << 12) + row * 64 + px)) * 16;
#pragma unroll
  for (int j = 0; j < 4; ++j) R[rbase + quad * 4 + j] = rpart[quad * 4 + j];
}

// ---------------------------------------------------------------------------
// K3: upsample+1x1+sigmoid from R maps, LDS-tiled (coalesced R reads).
// ---------------------------------------------------------------------------
__global__ __launch_bounds__(256) void k_upb(
    const float* __restrict__ R, float* __restrict__ out) {
  __shared__ float sR[10 * 10 * 16];   // 6.4 KB
  int b = blockIdx.x >> 6;
  int ty = (blockIdx.x >> 3) & 7, tx = blockIdx.x & 7;
  int Y0 = ty * 16, X0 = tx * 16;
  int ib = (Y0 >> 1) - 1, jb = (X0 >> 1) - 1;
  int t = threadIdx.x;
  const float* Rb = R + (((size_t)b) << 12) * 16;
  for (int idx = t; idx < 1600; idx += 256) {
    int ii = idx / 160, rem = idx - ii * 160;
    int jj = rem >> 4, tt = rem & 15;
    int gi = ib + ii, gj = jb + jj;
    float v = 0.f;
    if (((unsigned)gi < 64u) && ((unsigned)gj < 64u))
      v = Rb[(size_t)(gi * 64 + gj) * 16 + tt];
    sR[idx] = v;
  }
  __syncthreads();
  int X = X0 + (t & 15), Y = Y0 + (t >> 4);
  int li0, wu0, wu1, lj0, wv0, wv1;
  if (Y & 1) { li0 = ((Y - 1) >> 1) - ib; wu0 = 2; wu1 = 0; }
  else       { li0 = (Y / 2 - 1) - ib;    wu0 = 3; wu1 = 1; }
  if (X & 1) { lj0 = ((X - 1) >> 1) - jb; wv0 = 2; wv1 = 0; }
  else       { lj0 = (X / 2 - 1) - jb;    wv0 = 3; wv1 = 1; }
  int li1 = li0 + 1, lj1 = lj0 + 1;
  float s = sR[(li0 * 10 + lj0) * 16 + wu0 * 4 + wv0] +
            sR[(li0 * 10 + lj1) * 16 + wu0 * 4 + wv1] +
            sR[(li1 * 10 + lj0) * 16 + wu1 * 4 + wv0] +
            sR[(li1 * 10 + lj1) * 16 + wu1 * 4 + wv1];
  out[((size_t)b * 128 + Y) * 128 + X] = 1.f / (1.f + __expf(-s));
}

// ---------------------------------------------------------------------------
extern "C" void kernel_launch(void* const* d_in, const int* in_sizes, int n_in,
                              void* d_out, int out_size, void* d_ws, size_t ws_size,
                              hipStream_t stream) {
  const float* x        = (const float*)d_in[0];
  const float* w_dcn    = (const float*)d_in[1];
  const float* b_dcn    = (const float*)d_in[2];
  const float* w_off    = (const float*)d_in[3];
  const float* b_off    = (const float*)d_in[4];
  const float* bn_gamma = (const float*)d_in[5];
  const float* bn_beta  = (const float*)d_in[6];
  const float* bn_mean  = (const float*)d_in[7];
  const float* bn_var   = (const float*)d_in[8];
  const float* w_up     = (const float*)d_in[9];
  const float* w_1x1    = (const float*)d_in[10];
  float* out = (float*)d_out;

  // ws layout in FLOAT units (21.39 MB total):
  float* ws = (float*)d_ws;
  unsigned short* xT     = (unsigned short*)ws;                    // 8388608 ush
  unsigned short* wt_dcn = (unsigned short*)(ws + 4194304);        //  294912 ush
  unsigned short* wt_off = (unsigned short*)(ws + 4341760);        //   73728 ush
  float* vtab            = ws + 4378624;                           //    2048 f
  float* bntab           = ws + 4380672;                           //     256 f
  unsigned short* om     = (unsigned short*)(ws + 4380928);        //  884736 ush
  float* R               = ws + 4823296;                           //  524288 f

  k_pre<<<2176, 256, 0, stream>>>(x, w_dcn, w_off, b_dcn, bn_gamma, bn_beta,
                                  bn_mean, bn_var, w_up, w_1x1,
                                  xT, wt_dcn, wt_off, vtab, bntab);
  k_offconv<<<512, 256, 0, stream>>>(xT, wt_off, b_off, om);
  k_dcn<<<512, 256, 0, stream>>>(xT, wt_dcn, om, vtab, bntab, R);
  k_upb<<<512, 256, 0, stream>>>(R, out);
}